// Round 1
// 1632.248 us; speedup vs baseline: 1.7326x; 1.7326x over previous
//
#include <hip/hip_runtime.h>
#include <cstddef>
#include <cstdint>

// QuarotFP16Linear: out[M,N] = (X[M,K] * sx[M]) @ ((Wq[N,K] - off[N,G]) * ws[N,G])^T
// M=8192 (B*S), N=11008 (OUT), K=4096 (IN), GS=128, G=32.
//
// Round 1: two-pass. Pass 1 dequantizes X*sx and (Wq-off)*ws to bf16 in the
// workspace (runs the dequant ONCE instead of 86x/64x in the fused loop).
// Pass 2 is a pure bf16 MFMA GEMM in the m97 structure: 128x128 tile, BK=32,
// linear LDS (no pad -- required by global_load_lds), async global->LDS
// staging via __builtin_amdgcn_global_load_lds width=16.
// Fallback to the round-0 fused kernel if ws_size < 150 MiB.

typedef __attribute__((ext_vector_type(8))) short short8;    // mfma A/B frag (8 bf16)
typedef __attribute__((ext_vector_type(4))) short short4v;
typedef __attribute__((ext_vector_type(4))) float floatx4;

#define M_TOT 8192
#define N_TOT 11008
#define K_TOT 4096
#define GSZ   128
#define NG    32

#define BM 128
#define BN 128
#define BK 32
#define LDS_STRIDE 40   // fallback kernel only

typedef const __attribute__((address_space(1))) unsigned int guint;
typedef __attribute__((address_space(3))) unsigned int luint;

__device__ __forceinline__ short f2bf_rne(float f) {
    union { float f; unsigned u; } v; v.f = f;
    unsigned r = v.u + 0x7fffu + ((v.u >> 16) & 1u);   // round-to-nearest-even
    return (short)(r >> 16);
}

// ---------------- pass 1a: Xb[m,k] = bf16(X[m,k] * SX[m]) ----------------
__global__ __launch_bounds__(256)
void dequant_x_kernel(const float* __restrict__ X, const float* __restrict__ SX,
                      unsigned short* __restrict__ Xb) {
    const size_t i = ((size_t)blockIdx.x * 256 + threadIdx.x) * 8;
    const int row = (int)(i >> 12);            // / 4096
    const float s = SX[row];
    floatx4 v0 = *(const floatx4*)&X[i];
    floatx4 v1 = *(const floatx4*)&X[i + 4];
    short8 b;
    b[0] = f2bf_rne(v0.x * s); b[1] = f2bf_rne(v0.y * s);
    b[2] = f2bf_rne(v0.z * s); b[3] = f2bf_rne(v0.w * s);
    b[4] = f2bf_rne(v1.x * s); b[5] = f2bf_rne(v1.y * s);
    b[6] = f2bf_rne(v1.z * s); b[7] = f2bf_rne(v1.w * s);
    *(short8*)&Xb[i] = b;
}

// ------------- pass 1b: Wb[n,k] = bf16((Wq[n,k] - off[n,g]) * ws[n,g]) -------------
__global__ __launch_bounds__(256)
void dequant_w_kernel(const float* __restrict__ Wq, const float* __restrict__ WS,
                      const float* __restrict__ OFW, unsigned short* __restrict__ Wb) {
    const size_t i = ((size_t)blockIdx.x * 256 + threadIdx.x) * 8;
    const int row = (int)(i >> 12);            // / 4096
    const int g   = (int)((i >> 7) & 31);      // (k / 128), 8 elems never cross a group
    const float sc = WS[row * NG + g];
    const float of = OFW[row * NG + g];
    floatx4 v0 = *(const floatx4*)&Wq[i];
    floatx4 v1 = *(const floatx4*)&Wq[i + 4];
    short8 b;
    b[0] = f2bf_rne((v0.x - of) * sc); b[1] = f2bf_rne((v0.y - of) * sc);
    b[2] = f2bf_rne((v0.z - of) * sc); b[3] = f2bf_rne((v0.w - of) * sc);
    b[4] = f2bf_rne((v1.x - of) * sc); b[5] = f2bf_rne((v1.y - of) * sc);
    b[6] = f2bf_rne((v1.z - of) * sc); b[7] = f2bf_rne((v1.w - of) * sc);
    *(short8*)&Wb[i] = b;
}

// ---------------- pass 2: C[M,N] = A[M,K] @ B[N,K]^T, bf16 in, f32 out ----------------
// m97 structure: 4 waves, each computes 64x64 via 4x4 grid of 16x16x32 MFMAs.
// LDS is LINEAR [128][32] bf16 (64 B/row) -- global_load_lds writes
// wave-uniform base + lane*16, so no padding is possible.
__global__ __launch_bounds__(256)
void gemm_bf16_kernel(const unsigned short* __restrict__ A,
                      const unsigned short* __restrict__ B,
                      float* __restrict__ C) {
    __shared__ unsigned short As[BM * BK];   // 8 KB
    __shared__ unsigned short Bs[BN * BK];   // 8 KB

    const int t  = threadIdx.x;
    const int nt = blockIdx.x % (N_TOT / BN);   // 86
    const int mt = blockIdx.x / (N_TOT / BN);   // 64
    const int m0 = mt * BM;
    const int n0 = nt * BN;

    const int lane = t & 63;
    const int wave = t >> 6;
    const int wm   = (wave & 1) * 64;
    const int wn   = (wave >> 1) * 64;
    const int l15  = lane & 15;
    const int quad = lane >> 4;

    // Staging: each wave covers 32 rows (2 instructions x 16 rows) of each tile.
    // Per instruction, lane l supplies 16 B: row = seg*16 + l/4, col = (l&3)*8.
    const int rseg = lane >> 2;          // 0..15
    const int cseg = (lane & 3) * 8;     // 0,8,16,24

    const unsigned short* ga0 = A + (size_t)(m0 + wave * 32 + rseg) * K_TOT + cseg;
    const unsigned short* ga1 = ga0 + (size_t)16 * K_TOT;
    const unsigned short* gb0 = B + (size_t)(n0 + wave * 32 + rseg) * K_TOT + cseg;
    const unsigned short* gb1 = gb0 + (size_t)16 * K_TOT;

    // Wave-uniform LDS bases: seg = wave*2 + i -> ushort offset seg*512.
    unsigned short* lA0 = As + wave * 1024;
    unsigned short* lA1 = As + wave * 1024 + 512;
    unsigned short* lB0 = Bs + wave * 1024;
    unsigned short* lB1 = Bs + wave * 1024 + 512;

    floatx4 acc[4][4];
#pragma unroll
    for (int i = 0; i < 4; ++i)
#pragma unroll
        for (int j = 0; j < 4; ++j)
            acc[i][j] = (floatx4)0.0f;

    for (int kt = 0; kt < K_TOT / BK; ++kt) {
        __syncthreads();   // previous iteration's readers are done
        __builtin_amdgcn_global_load_lds((guint*)ga0, (luint*)lA0, 16, 0, 0);
        __builtin_amdgcn_global_load_lds((guint*)ga1, (luint*)lA1, 16, 0, 0);
        __builtin_amdgcn_global_load_lds((guint*)gb0, (luint*)lB0, 16, 0, 0);
        __builtin_amdgcn_global_load_lds((guint*)gb1, (luint*)lB1, 16, 0, 0);
        ga0 += BK; ga1 += BK; gb0 += BK; gb1 += BK;
        __syncthreads();   // compiler drains vmcnt(0) before this barrier

        short8 af[4], bf[4];
#pragma unroll
        for (int i = 0; i < 4; ++i)
            af[i] = *(const short8*)&As[(wm + i * 16 + l15) * BK + quad * 8];
#pragma unroll
        for (int j = 0; j < 4; ++j)
            bf[j] = *(const short8*)&Bs[(wn + j * 16 + l15) * BK + quad * 8];
#pragma unroll
        for (int i = 0; i < 4; ++i)
#pragma unroll
            for (int j = 0; j < 4; ++j)
                acc[i][j] = __builtin_amdgcn_mfma_f32_16x16x32_bf16(af[i], bf[j], acc[i][j], 0, 0, 0);
    }

    // Epilogue: D[m = quad*4 + r][n = l15] per 16x16 frag.
#pragma unroll
    for (int i = 0; i < 4; ++i) {
        const int row_base = m0 + wm + i * 16 + quad * 4;
#pragma unroll
        for (int j = 0; j < 4; ++j) {
            const int col = n0 + wn + j * 16 + l15;
#pragma unroll
            for (int r = 0; r < 4; ++r)
                C[(size_t)(row_base + r) * N_TOT + col] = acc[i][j][r];
        }
    }
}

// ---------------- round-0 fused kernel (fallback if workspace too small) ----------------
__global__ __launch_bounds__(256)
void qgemm_kernel(const float* __restrict__ X, const float* __restrict__ SX,
                  const float* __restrict__ Wq, const float* __restrict__ WS,
                  const float* __restrict__ OFW, float* __restrict__ OUT) {
    __shared__ short As[BM * LDS_STRIDE];
    __shared__ short Bs[BN * LDS_STRIDE];

    const int t  = threadIdx.x;
    const int nt = blockIdx.x % (N_TOT / BN);
    const int mt = blockIdx.x / (N_TOT / BN);
    const int m0 = mt * BM;
    const int n0 = nt * BN;

    const int lane = t & 63;
    const int wave = t >> 6;
    const int wm   = (wave & 1) * 64;
    const int wn   = (wave >> 1) * 64;
    const int l15  = lane & 15;
    const int quad = lane >> 4;

    const int srow = t >> 3;
    const int scol = (t & 7) * 4;

    floatx4 acc[4][4];
#pragma unroll
    for (int i = 0; i < 4; ++i)
#pragma unroll
        for (int j = 0; j < 4; ++j)
            acc[i][j] = (floatx4)0.0f;

    float ascale[4];
#pragma unroll
    for (int j = 0; j < 4; ++j)
        ascale[j] = SX[m0 + j * 32 + srow];

    for (int g = 0; g < NG; ++g) {
        float wsv[4], ofv[4];
#pragma unroll
        for (int j = 0; j < 4; ++j) {
            const int n = n0 + j * 32 + srow;
            wsv[j] = WS[n * NG + g];
            ofv[j] = OFW[n * NG + g];
        }
        for (int kk = 0; kk < GSZ / BK; ++kk) {
            const int k0 = g * GSZ + kk * BK;
            __syncthreads();
#pragma unroll
            for (int j = 0; j < 4; ++j) {
                const int r = j * 32 + srow;
                floatx4 v = *(const floatx4*)&X[(size_t)(m0 + r) * K_TOT + k0 + scol];
                const float s = ascale[j];
                short4v b;
                b.x = f2bf_rne(v.x * s);
                b.y = f2bf_rne(v.y * s);
                b.z = f2bf_rne(v.z * s);
                b.w = f2bf_rne(v.w * s);
                *(short4v*)&As[r * LDS_STRIDE + scol] = b;
            }
#pragma unroll
            for (int j = 0; j < 4; ++j) {
                const int r = j * 32 + srow;
                floatx4 v = *(const floatx4*)&Wq[(size_t)(n0 + r) * K_TOT + k0 + scol];
                const float sc = wsv[j], of = ofv[j];
                short4v b;
                b.x = f2bf_rne((v.x - of) * sc);
                b.y = f2bf_rne((v.y - of) * sc);
                b.z = f2bf_rne((v.z - of) * sc);
                b.w = f2bf_rne((v.w - of) * sc);
                *(short4v*)&Bs[r * LDS_STRIDE + scol] = b;
            }
            __syncthreads();
            short8 af[4], bf[4];
#pragma unroll
            for (int i = 0; i < 4; ++i)
                af[i] = *(const short8*)&As[(wm + i * 16 + l15) * LDS_STRIDE + quad * 8];
#pragma unroll
            for (int i = 0; i < 4; ++i)
                bf[i] = *(const short8*)&Bs[(wn + i * 16 + l15) * LDS_STRIDE + quad * 8];
#pragma unroll
            for (int i = 0; i < 4; ++i)
#pragma unroll
                for (int j = 0; j < 4; ++j)
                    acc[i][j] = __builtin_amdgcn_mfma_f32_16x16x32_bf16(af[i], bf[j], acc[i][j], 0, 0, 0);
        }
    }

#pragma unroll
    for (int i = 0; i < 4; ++i) {
        const int row_base = m0 + wm + i * 16 + quad * 4;
#pragma unroll
        for (int j = 0; j < 4; ++j) {
            const int col = n0 + wn + j * 16 + l15;
#pragma unroll
            for (int r = 0; r < 4; ++r)
                OUT[(size_t)(row_base + r) * N_TOT + col] = acc[i][j][r];
        }
    }
}

extern "C" void kernel_launch(void* const* d_in, const int* in_sizes, int n_in,
                              void* d_out, int out_size, void* d_ws, size_t ws_size,
                              hipStream_t stream) {
    const float* X   = (const float*)d_in[0];   // quantized_x [B,S,IN]
    const float* SX  = (const float*)d_in[1];   // scales_x    [B,S,1]
    const float* Wq  = (const float*)d_in[2];   // weight      [OUT,IN]
    const float* WS  = (const float*)d_in[3];   // weight_scales [OUT,G]
    const float* OFW = (const float*)d_in[4];   // offset_w    [OUT,G]
    float* out = (float*)d_out;

    const size_t xb_bytes = (size_t)M_TOT * K_TOT * 2;   // 64 MiB
    const size_t wb_bytes = (size_t)N_TOT * K_TOT * 2;   // 86 MiB
    const int grid_gemm = (M_TOT / BM) * (N_TOT / BN);   // 64 * 86 = 5504

    if (ws_size >= xb_bytes + wb_bytes) {
        unsigned short* Xb = (unsigned short*)d_ws;
        unsigned short* Wb = (unsigned short*)((char*)d_ws + xb_bytes);
        const int grid_x = (int)(((size_t)M_TOT * K_TOT / 8) / 256);   // 16384
        const int grid_w = (int)(((size_t)N_TOT * K_TOT / 8) / 256);   // 22016
        dequant_x_kernel<<<grid_x, 256, 0, stream>>>(X, SX, Xb);
        dequant_w_kernel<<<grid_w, 256, 0, stream>>>(Wq, WS, OFW, Wb);
        gemm_bf16_kernel<<<grid_gemm, 256, 0, stream>>>(Xb, Wb, out);
    } else {
        qgemm_kernel<<<grid_gemm, 256, 0, stream>>>(X, SX, Wq, WS, OFW, out);
    }
}

// Round 2
// 1296.761 us; speedup vs baseline: 2.1809x; 1.2587x over previous
//
#include <hip/hip_runtime.h>
#include <cstddef>
#include <cstdint>

// QuarotFP16Linear: out[M,N] = (X[M,K] * sx[M]) @ ((Wq[N,K] - off[N,G]) * ws[N,G])^T
// M=8192, N=11008, K=4096, GS=128, G=32.
//
// Round 2: two-pass (dequant once to bf16 workspace) + deep-pipelined GEMM:
//   256x256 tile, 8 waves, BK=32, 4-deep circular LDS buffer (128 KiB),
//   counted s_waitcnt vmcnt(12) (never drain-to-0), raw s_barrier,
//   T2 XOR-swizzled LDS (linear gload_lds dest + pre-swizzled global source),
//   T5 setprio around MFMA cluster, T1 XCD-aware block swizzle.

typedef __attribute__((ext_vector_type(8))) short short8;    // mfma A/B frag (8 bf16)
typedef __attribute__((ext_vector_type(4))) short short4v;
typedef __attribute__((ext_vector_type(4))) float floatx4;

#define M_TOT 8192
#define N_TOT 11008
#define K_TOT 4096
#define GSZ   128
#define NG    32

// GEMM geometry
#define BM 256
#define BN 256
#define BK 32
#define NT (K_TOT / BK)        // 128 K-tiles
#define TILE_U16 (256 * 32)    // 8192 ushorts = 16 KiB per A- or B-tile
#define HALF_U16 4096

// fused fallback only
#define FBM 128
#define FBN 128
#define LDS_STRIDE 40

typedef const __attribute__((address_space(1))) unsigned int guint;
typedef __attribute__((address_space(3))) unsigned int luint;

__device__ __forceinline__ short f2bf_rne(float f) {
    union { float f; unsigned u; } v; v.f = f;
    unsigned r = v.u + 0x7fffu + ((v.u >> 16) & 1u);   // round-to-nearest-even
    return (short)(r >> 16);
}

template<int N> __device__ __forceinline__ void vm_wait_barrier() {
    asm volatile("s_waitcnt vmcnt(%0)" :: "n"(N) : "memory");
    __builtin_amdgcn_s_barrier();
    __builtin_amdgcn_sched_barrier(0);   // nothing crosses the barrier (rule 18)
}

__device__ __forceinline__ void end_barrier() {
    asm volatile("" ::: "memory");
    __builtin_amdgcn_s_barrier();
    asm volatile("" ::: "memory");
}

// ---------------- pass 1a: Xb[m,k] = bf16(X[m,k] * SX[m]) ----------------
// 32 elems/thread; 32 | i and 4096-elem rows => one SX scalar per thread.
__global__ __launch_bounds__(256)
void dequant_x_kernel(const float* __restrict__ X, const float* __restrict__ SX,
                      unsigned short* __restrict__ Xb) {
    const size_t i0 = ((size_t)blockIdx.x * 256 + threadIdx.x) * 32;
    const float s = SX[i0 >> 12];
#pragma unroll
    for (int c = 0; c < 4; ++c) {
        const size_t i = i0 + c * 8;
        floatx4 v0 = *(const floatx4*)&X[i];
        floatx4 v1 = *(const floatx4*)&X[i + 4];
        short8 b;
        b[0] = f2bf_rne(v0.x * s); b[1] = f2bf_rne(v0.y * s);
        b[2] = f2bf_rne(v0.z * s); b[3] = f2bf_rne(v0.w * s);
        b[4] = f2bf_rne(v1.x * s); b[5] = f2bf_rne(v1.y * s);
        b[6] = f2bf_rne(v1.z * s); b[7] = f2bf_rne(v1.w * s);
        *(short8*)&Xb[i] = b;
    }
}

// ------------- pass 1b: Wb[n,k] = bf16((Wq[n,k] - off[n,g]) * ws[n,g]) -------------
// 32 elems/thread never cross a 128-elem group => one ws/of pair per thread.
__global__ __launch_bounds__(256)
void dequant_w_kernel(const float* __restrict__ Wq, const float* __restrict__ WS,
                      const float* __restrict__ OFW, unsigned short* __restrict__ Wb) {
    const size_t i0 = ((size_t)blockIdx.x * 256 + threadIdx.x) * 32;
    const int row = (int)(i0 >> 12);
    const int g   = (int)((i0 >> 7) & 31);
    const float sc = WS[row * NG + g];
    const float of = OFW[row * NG + g];
#pragma unroll
    for (int c = 0; c < 4; ++c) {
        const size_t i = i0 + c * 8;
        floatx4 v0 = *(const floatx4*)&Wq[i];
        floatx4 v1 = *(const floatx4*)&Wq[i + 4];
        short8 b;
        b[0] = f2bf_rne((v0.x - of) * sc); b[1] = f2bf_rne((v0.y - of) * sc);
        b[2] = f2bf_rne((v0.z - of) * sc); b[3] = f2bf_rne((v0.w - of) * sc);
        b[4] = f2bf_rne((v1.x - of) * sc); b[5] = f2bf_rne((v1.y - of) * sc);
        b[6] = f2bf_rne((v1.z - of) * sc); b[7] = f2bf_rne((v1.w - of) * sc);
        *(short8*)&Wb[i] = b;
    }
}

// ---------------- pass 2: C[M,N] = A[M,K] @ B[N,K]^T, bf16 in, f32 out ----------------
// 8 waves as 2(M) x 4(N); each wave computes 128x64 via 8x4 grid of 16x16x32 MFMAs.
// LDS swizzle (involution on byte offset within a tile): b ^= ((b>>7)&3)<<4
//   - write: gload_lds dest is LINEAR, global source address pre-swizzled
//   - read: ds_read_b128 at swizzled offset -> 2-way banks (free)
__global__ __launch_bounds__(512, 2)
void gemm_bf16_kernel(const unsigned short* __restrict__ A,
                      const unsigned short* __restrict__ B,
                      float* __restrict__ C) {
    __shared__ alignas(16) unsigned short lds[4 * 2 * TILE_U16];   // 128 KiB

    const int t    = threadIdx.x;
    const int lane = t & 63;
    const int wave = t >> 6;

    // T1: XCD-aware swizzle; nwg = 32*43 = 1376 = 8*172 (divisible -> bijective)
    const int bid  = blockIdx.x;
    const int swzb = (bid & 7) * 172 + (bid >> 3);
    const int mt = swzb / (N_TOT / BN);
    const int nt = swzb % (N_TOT / BN);
    const int m0 = mt * BM;
    const int n0 = nt * BN;

    const int wm   = (wave & 1) * 128;   // wave's M offset
    const int wn   = (wave >> 1) * 64;   // wave's N offset
    const int l15  = lane & 15;
    const int quad = lane >> 4;

    // ---- staging: linear LDS dest byte d = q*8192 + t*16; global src = swz(d) ----
    int rowS[2], cbS[2];
#pragma unroll
    for (int q = 0; q < 2; ++q) {
        const int d = q * 8192 + t * 16;
        const int s = d ^ (((d >> 7) & 3) << 4);
        rowS[q] = s >> 6;          // 0..255 (swz keeps row bits)
        cbS[q]  = (s & 63) >> 1;   // ushort col, multiple of 8
    }
    const unsigned short* gA0 = A + (size_t)(m0 + rowS[0]) * K_TOT + cbS[0];
    const unsigned short* gA1 = A + (size_t)(m0 + rowS[1]) * K_TOT + cbS[1];
    const unsigned short* gB0 = B + (size_t)(n0 + rowS[0]) * K_TOT + cbS[0];
    const unsigned short* gB1 = B + (size_t)(n0 + rowS[1]) * K_TOT + cbS[1];

    // ---- fragment read offsets (swizzled, ushort units), loop-invariant ----
    int offA[8], offB[4];
#pragma unroll
    for (int i = 0; i < 8; ++i) {
        const int u = (wm + i * 16 + l15) * BK + quad * 8;
        offA[i] = u ^ (((u >> 6) & 3) << 3);
    }
#pragma unroll
    for (int j = 0; j < 4; ++j) {
        const int u = (wn + j * 16 + l15) * BK + quad * 8;
        offB[j] = u ^ (((u >> 6) & 3) << 3);
    }

    floatx4 acc[8][4];
#pragma unroll
    for (int i = 0; i < 8; ++i)
#pragma unroll
        for (int j = 0; j < 4; ++j)
            acc[i][j] = (floatx4)0.0f;

    auto STAGE = [&](int tt) {
        const int b  = tt & 3;
        const int kk = (tt < NT ? tt : tt - NT) * BK;   // tail wraps (data unused)
        unsigned short* base = &lds[b * 2 * TILE_U16];
        __builtin_amdgcn_global_load_lds((guint*)(gA0 + kk), (luint*)(base + wave * 512), 16, 0, 0);
        __builtin_amdgcn_global_load_lds((guint*)(gA1 + kk), (luint*)(base + HALF_U16 + wave * 512), 16, 0, 0);
        __builtin_amdgcn_global_load_lds((guint*)(gB0 + kk), (luint*)(base + TILE_U16 + wave * 512), 16, 0, 0);
        __builtin_amdgcn_global_load_lds((guint*)(gB1 + kk), (luint*)(base + TILE_U16 + HALF_U16 + wave * 512), 16, 0, 0);
    };

    STAGE(0); STAGE(1); STAGE(2);   // 12 instrs in flight

    for (int kt = 0; kt < NT; ++kt) {
        STAGE(kt + 3);              // 16 in flight
        vm_wait_barrier<12>();      // retire exactly stage kt; barrier; sched fence

        const unsigned short* As = &lds[(kt & 3) * 2 * TILE_U16];
        const unsigned short* Bs = As + TILE_U16;
        short8 af[8], bf[4];
#pragma unroll
        for (int i = 0; i < 8; ++i) af[i] = *(const short8*)(As + offA[i]);
#pragma unroll
        for (int j = 0; j < 4; ++j) bf[j] = *(const short8*)(Bs + offB[j]);

        __builtin_amdgcn_s_setprio(1);
#pragma unroll
        for (int i = 0; i < 8; ++i)
#pragma unroll
            for (int j = 0; j < 4; ++j)
                acc[i][j] = __builtin_amdgcn_mfma_f32_16x16x32_bf16(af[i], bf[j], acc[i][j], 0, 0, 0);
        __builtin_amdgcn_s_setprio(0);

        end_barrier();              // all reads of buf[kt&3] done before its overwrite
    }

    // ---- epilogue: D[m = quad*4 + r][n = l15] per 16x16 frag ----
#pragma unroll
    for (int i = 0; i < 8; ++i) {
        const int row_base = m0 + wm + i * 16 + quad * 4;
#pragma unroll
        for (int j = 0; j < 4; ++j) {
            const int col = n0 + wn + j * 16 + l15;
#pragma unroll
            for (int r = 0; r < 4; ++r)
                C[(size_t)(row_base + r) * N_TOT + col] = acc[i][j][r];
        }
    }
}

// ---------------- round-0 fused kernel (fallback if workspace too small) ----------------
__global__ __launch_bounds__(256)
void qgemm_kernel(const float* __restrict__ X, const float* __restrict__ SX,
                  const float* __restrict__ Wq, const float* __restrict__ WS,
                  const float* __restrict__ OFW, float* __restrict__ OUT) {
    __shared__ short As[FBM * LDS_STRIDE];
    __shared__ short Bs[FBN * LDS_STRIDE];

    const int t  = threadIdx.x;
    const int nt = blockIdx.x % (N_TOT / FBN);
    const int mt = blockIdx.x / (N_TOT / FBN);
    const int m0 = mt * FBM;
    const int n0 = nt * FBN;

    const int lane = t & 63;
    const int wave = t >> 6;
    const int wm   = (wave & 1) * 64;
    const int wn   = (wave >> 1) * 64;
    const int l15  = lane & 15;
    const int quad = lane >> 4;

    const int srow = t >> 3;
    const int scol = (t & 7) * 4;

    floatx4 acc[4][4];
#pragma unroll
    for (int i = 0; i < 4; ++i)
#pragma unroll
        for (int j = 0; j < 4; ++j)
            acc[i][j] = (floatx4)0.0f;

    float ascale[4];
#pragma unroll
    for (int j = 0; j < 4; ++j)
        ascale[j] = SX[m0 + j * 32 + srow];

    for (int g = 0; g < NG; ++g) {
        float wsv[4], ofv[4];
#pragma unroll
        for (int j = 0; j < 4; ++j) {
            const int n = n0 + j * 32 + srow;
            wsv[j] = WS[n * NG + g];
            ofv[j] = OFW[n * NG + g];
        }
        for (int kk = 0; kk < GSZ / BK; ++kk) {
            const int k0 = g * GSZ + kk * BK;
            __syncthreads();
#pragma unroll
            for (int j = 0; j < 4; ++j) {
                const int r = j * 32 + srow;
                floatx4 v = *(const floatx4*)&X[(size_t)(m0 + r) * K_TOT + k0 + scol];
                const float s = ascale[j];
                short4v b;
                b.x = f2bf_rne(v.x * s);
                b.y = f2bf_rne(v.y * s);
                b.z = f2bf_rne(v.z * s);
                b.w = f2bf_rne(v.w * s);
                *(short4v*)&As[r * LDS_STRIDE + scol] = b;
            }
#pragma unroll
            for (int j = 0; j < 4; ++j) {
                const int r = j * 32 + srow;
                floatx4 v = *(const floatx4*)&Wq[(size_t)(n0 + r) * K_TOT + k0 + scol];
                const float sc = wsv[j], of = ofv[j];
                short4v b;
                b.x = f2bf_rne((v.x - of) * sc);
                b.y = f2bf_rne((v.y - of) * sc);
                b.z = f2bf_rne((v.z - of) * sc);
                b.w = f2bf_rne((v.w - of) * sc);
                *(short4v*)&Bs[r * LDS_STRIDE + scol] = b;
            }
            __syncthreads();
            short8 af[4], bf[4];
#pragma unroll
            for (int i = 0; i < 4; ++i)
                af[i] = *(const short8*)&As[(wm + i * 16 + l15) * LDS_STRIDE + quad * 8];
#pragma unroll
            for (int i = 0; i < 4; ++i)
                bf[i] = *(const short8*)&Bs[(wn + i * 16 + l15) * LDS_STRIDE + quad * 8];
#pragma unroll
            for (int i = 0; i < 4; ++i)
#pragma unroll
                for (int j = 0; j < 4; ++j)
                    acc[i][j] = __builtin_amdgcn_mfma_f32_16x16x32_bf16(af[i], bf[j], acc[i][j], 0, 0, 0);
        }
    }

#pragma unroll
    for (int i = 0; i < 4; ++i) {
        const int row_base = m0 + wm + i * 16 + quad * 4;
#pragma unroll
        for (int j = 0; j < 4; ++j) {
            const int col = n0 + wn + j * 16 + l15;
#pragma unroll
            for (int r = 0; r < 4; ++r)
                OUT[(size_t)(row_base + r) * N_TOT + col] = acc[i][j][r];
        }
    }
}

extern "C" void kernel_launch(void* const* d_in, const int* in_sizes, int n_in,
                              void* d_out, int out_size, void* d_ws, size_t ws_size,
                              hipStream_t stream) {
    const float* X   = (const float*)d_in[0];   // quantized_x [B,S,IN]
    const float* SX  = (const float*)d_in[1];   // scales_x    [B,S,1]
    const float* Wq  = (const float*)d_in[2];   // weight      [OUT,IN]
    const float* WS  = (const float*)d_in[3];   // weight_scales [OUT,G]
    const float* OFW = (const float*)d_in[4];   // offset_w    [OUT,G]
    float* out = (float*)d_out;

    const size_t xb_bytes = (size_t)M_TOT * K_TOT * 2;   // 64 MiB
    const size_t wb_bytes = (size_t)N_TOT * K_TOT * 2;   // 86 MiB

    if (ws_size >= xb_bytes + wb_bytes) {
        unsigned short* Xb = (unsigned short*)d_ws;
        unsigned short* Wb = (unsigned short*)((char*)d_ws + xb_bytes);
        const int grid_x = (int)(((size_t)M_TOT * K_TOT / 32) / 256);   // 4096
        const int grid_w = (int)(((size_t)N_TOT * K_TOT / 32) / 256);   // 5504
        const int grid_gemm = (M_TOT / BM) * (N_TOT / BN);              // 32*43 = 1376
        dequant_x_kernel<<<grid_x, 256, 0, stream>>>(X, SX, Xb);
        dequant_w_kernel<<<grid_w, 256, 0, stream>>>(Wq, WS, OFW, Wb);
        gemm_bf16_kernel<<<grid_gemm, 512, 0, stream>>>(Xb, Wb, out);
    } else {
        const int grid = (M_TOT / FBM) * (N_TOT / FBN);
        qgemm_kernel<<<grid, 256, 0, stream>>>(X, SX, Wq, WS, OFW, out);
    }
}

// Round 4
// 1141.680 us; speedup vs baseline: 2.4771x; 1.1358x over previous
//
#include <hip/hip_runtime.h>
#include <cstddef>
#include <cstdint>

// QuarotFP16Linear: out[M,N] = (X[M,K] * sx[M]) @ ((Wq[N,K] - off[N,G]) * ws[N,G])^T
// M=8192, N=11008, K=4096, GS=128, G=32.
//
// Round 4: resubmission of round 3 (container-level infra failure, no kernel
// data). Two-pass (dequant once to bf16 workspace) + 8-phase 256x256 GEMM
// (m201 template): BK=64, 8 waves, half-tile-granular staging, counted
// vmcnt(4) at phases 4/8 only, 3-bit XOR LDS swizzle (write-side via
// pre-swizzled global source, read-side via XOR'd ds_read addr), setprio
// around each 16-MFMA cluster, XCD-aware block swizzle.
//
// Split-half wave mapping (the 8-phase enabler): wave's m-quad q reads
// A-half q at rows (wave&1)*64..+64; n-quad q reads B-half q at rows
// (wave>>1)*32..+32. Each half-tile's LDS liveness ends mid-K-tile, so
// half-tiles are staged one-per-phase with >=4 phases of latency cover.
//
// Audited invariants (round-3 post-mortem):
//  - vmcnt in-order retirement: ph4/ph8 vmcnt(4) retires exactly the
//    next-needed K-tile's 8 loads, leaving the 4 newest in flight.
//  - every LDS overwrite is >=1 full barrier after the last read of the
//    previous contents (ph1<-prev ph7, ph3<-ph1, ph5<-ph2/ph3, ph7<-ph5).
//  - all barriers wave-uniform; swizzle is a bits-4..6 involution.

typedef __attribute__((ext_vector_type(8))) short short8;    // mfma A/B frag (8 bf16)
typedef __attribute__((ext_vector_type(4))) short short4v;
typedef __attribute__((ext_vector_type(4))) float floatx4;

#define M_TOT 8192
#define N_TOT 11008
#define K_TOT 4096
#define GSZ   128
#define NG    32

#define BM 256
#define BN 256
#define BK 64
#define NTILE (K_TOT / BK)   // 64 K-tiles
#define NITER (NTILE / 2)    // 32 iterations, 2 K-tiles each

// fused fallback only
#define FBM 128
#define FBN 128
#define LDS_STRIDE 40

typedef const __attribute__((address_space(1))) unsigned int guint;
typedef __attribute__((address_space(3))) unsigned int luint;

__device__ __forceinline__ short f2bf_rne(float f) {
    union { float f; unsigned u; } v; v.f = f;
    unsigned r = v.u + 0x7fffu + ((v.u >> 16) & 1u);   // round-to-nearest-even
    return (short)(r >> 16);
}

__device__ __forceinline__ void fence_barrier() {
    asm volatile("" ::: "memory");
    __builtin_amdgcn_s_barrier();
    asm volatile("" ::: "memory");
}

// ---------------- pass 1a: Xb[m,k] = bf16(X[m,k] * SX[m]) ----------------
__global__ __launch_bounds__(256)
void dequant_x_kernel(const float* __restrict__ X, const float* __restrict__ SX,
                      unsigned short* __restrict__ Xb) {
    const size_t i = ((size_t)blockIdx.x * 256 + threadIdx.x) * 8;
    const float s = SX[i >> 12];
    floatx4 v0 = *(const floatx4*)&X[i];
    floatx4 v1 = *(const floatx4*)&X[i + 4];
    short8 b;
    b[0] = f2bf_rne(v0.x * s); b[1] = f2bf_rne(v0.y * s);
    b[2] = f2bf_rne(v0.z * s); b[3] = f2bf_rne(v0.w * s);
    b[4] = f2bf_rne(v1.x * s); b[5] = f2bf_rne(v1.y * s);
    b[6] = f2bf_rne(v1.z * s); b[7] = f2bf_rne(v1.w * s);
    *(short8*)&Xb[i] = b;
}

// ------------- pass 1b: Wb[n,k] = bf16((Wq[n,k] - off[n,g]) * ws[n,g]) -------------
__global__ __launch_bounds__(256)
void dequant_w_kernel(const float* __restrict__ Wq, const float* __restrict__ WS,
                      const float* __restrict__ OFW, unsigned short* __restrict__ Wb) {
    const size_t i = ((size_t)blockIdx.x * 256 + threadIdx.x) * 8;
    const int row = (int)(i >> 12);
    const int g   = (int)((i >> 7) & 31);
    const float sc = WS[row * NG + g];
    const float of = OFW[row * NG + g];
    floatx4 v0 = *(const floatx4*)&Wq[i];
    floatx4 v1 = *(const floatx4*)&Wq[i + 4];
    short8 b;
    b[0] = f2bf_rne((v0.x - of) * sc); b[1] = f2bf_rne((v0.y - of) * sc);
    b[2] = f2bf_rne((v0.z - of) * sc); b[3] = f2bf_rne((v0.w - of) * sc);
    b[4] = f2bf_rne((v1.x - of) * sc); b[5] = f2bf_rne((v1.y - of) * sc);
    b[6] = f2bf_rne((v1.z - of) * sc); b[7] = f2bf_rne((v1.w - of) * sc);
    *(short8*)&Wb[i] = b;
}

// ---------------- pass 2: 8-phase 256x256 bf16 GEMM ----------------
// LDS (u16 units): A half (slot,h) at (slot*2+h)*8192 ; B at +32768.
// Half-tile = [128 rows][64 cols] u16, row stride 128 B.
// Swizzle involution on byte offset within a half: b ^= ((b>>7)&7)<<4.

#define STAGE_A(tt, h) { \
    const int sl_ = (tt) & 1; const int kc_ = ((tt) & 63) * BK; \
    unsigned short* d_ = lds + (sl_ * 2 + (h)) * 8192 + wave * 512; \
    __builtin_amdgcn_global_load_lds((guint*)(pA0 + (size_t)(h) * 524288 + kc_), (luint*)d_, 16, 0, 0); \
    __builtin_amdgcn_global_load_lds((guint*)(pA1 + (size_t)(h) * 524288 + kc_), (luint*)(d_ + 4096), 16, 0, 0); }

#define STAGE_B(tt, h) { \
    const int sl_ = (tt) & 1; const int kc_ = ((tt) & 63) * BK; \
    unsigned short* d_ = lds + 32768 + (sl_ * 2 + (h)) * 8192 + wave * 512; \
    __builtin_amdgcn_global_load_lds((guint*)(pB0 + (size_t)(h) * 524288 + kc_), (luint*)d_, 16, 0, 0); \
    __builtin_amdgcn_global_load_lds((guint*)(pB1 + (size_t)(h) * 524288 + kc_), (luint*)(d_ + 4096), 16, 0, 0); }

#define LOADA(sl, mq) { \
    const char* base_ = (const char*)lds + ((sl) * 2 + (mq)) * 16384; \
    _Pragma("unroll") \
    for (int i_ = 0; i_ < 4; ++i_) { \
        const int rb_ = (mrow + i_ * 16 + l15) * 128; \
        a[i_][0] = *(const short8*)(base_ + rb_ + cK0); \
        a[i_][1] = *(const short8*)(base_ + rb_ + cK1); } }

#define LOADB(sl, nq) { \
    const char* base_ = (const char*)lds + 65536 + ((sl) * 2 + (nq)) * 16384; \
    _Pragma("unroll") \
    for (int j_ = 0; j_ < 2; ++j_) { \
        const int rb_ = (nrow + j_ * 16 + l15) * 128; \
        b[nq][j_][0] = *(const short8*)(base_ + rb_ + cK0); \
        b[nq][j_][1] = *(const short8*)(base_ + rb_ + cK1); } }

#define PH_SYNC() { fence_barrier(); \
    asm volatile("s_waitcnt lgkmcnt(0)" ::: "memory"); \
    __builtin_amdgcn_sched_barrier(0); }

#define MFMA16(mq, nq) { \
    __builtin_amdgcn_s_setprio(1); \
    _Pragma("unroll") \
    for (int i_ = 0; i_ < 4; ++i_) \
    _Pragma("unroll") \
    for (int j_ = 0; j_ < 2; ++j_) { \
        acc[mq][nq][i_][j_] = __builtin_amdgcn_mfma_f32_16x16x32_bf16(a[i_][0], b[nq][j_][0], acc[mq][nq][i_][j_], 0, 0, 0); \
        acc[mq][nq][i_][j_] = __builtin_amdgcn_mfma_f32_16x16x32_bf16(a[i_][1], b[nq][j_][1], acc[mq][nq][i_][j_], 0, 0, 0); } \
    __builtin_amdgcn_s_setprio(0); }

#define VMW4() asm volatile("s_waitcnt vmcnt(4)" ::: "memory");

__global__ __launch_bounds__(512, 2)
void gemm_bf16_kernel(const unsigned short* __restrict__ A,
                      const unsigned short* __restrict__ B,
                      float* __restrict__ C) {
    __shared__ alignas(16) unsigned short lds[65536];   // 128 KiB

    const int t    = threadIdx.x;
    const int lane = t & 63;
    const int wave = t >> 6;

    // T1: XCD swizzle; nwg = 32*43 = 1376 = 8*172 (divisible -> bijective)
    const int bid  = blockIdx.x;
    const int swzb = (bid & 7) * 172 + (bid >> 3);
    const int mt = swzb / (N_TOT / BN);
    const int nt = swzb % (N_TOT / BN);
    const int m0 = mt * BM;
    const int n0 = nt * BN;

    const int l15  = lane & 15;
    const int quad = lane >> 4;
    const int mrow = (wave & 1) * 64;    // A row base within a half
    const int nrow = (wave >> 1) * 32;   // B row base within a half

    // read-side swizzle: row&7 == l15&7 for every fragment row
    const int xmask = (l15 & 7) << 4;
    const int cK0 = (quad * 16) ^ xmask;        // kk=0 byte col
    const int cK1 = (64 + quad * 16) ^ xmask;   // kk=1

    // write-side: linear LDS dest d -> pre-swizzled global source s
    int rowS[2], colS[2];
#pragma unroll
    for (int q = 0; q < 2; ++q) {
        const int d = q * 8192 + t * 16;                 // byte within 16 KiB half
        const int s = d ^ (((d >> 7) & 7) << 4);
        rowS[q] = s >> 7;                                // 0..127
        colS[q] = (s & 127) >> 1;                        // u16 col, mult of 8
    }
    const unsigned short* pA0 = A + (size_t)(m0 + rowS[0]) * K_TOT + colS[0];
    const unsigned short* pA1 = A + (size_t)(m0 + rowS[1]) * K_TOT + colS[1];
    const unsigned short* pB0 = B + (size_t)(n0 + rowS[0]) * K_TOT + colS[0];
    const unsigned short* pB1 = B + (size_t)(n0 + rowS[1]) * K_TOT + colS[1];

    floatx4 acc[2][2][4][2];
#pragma unroll
    for (int mq = 0; mq < 2; ++mq)
#pragma unroll
    for (int nq = 0; nq < 2; ++nq)
#pragma unroll
    for (int i = 0; i < 4; ++i)
#pragma unroll
    for (int j = 0; j < 2; ++j)
        acc[mq][nq][i][j] = (floatx4)0.0f;

    short8 a[4][2];      // current m-quad subtile
    short8 b[2][2][2];   // [nq][j][kk], both n-quads kept

    // prologue: tile0 all halves + tile1 A0,B0 (12 loads)
    STAGE_A(0, 0); STAGE_B(0, 0); STAGE_A(0, 1); STAGE_B(0, 1);
    STAGE_A(1, 0); STAGE_B(1, 0);
    VMW4();            // retire tile 0; leave A0(1),B0(1) in flight
    fence_barrier();

    for (int I = 0; I < NITER; ++I) {
        const int u = 2 * I;                       // slot 0; u+1 slot 1
        // ph1: (m0,n0) of u
        LOADA(0, 0); LOADB(0, 0); STAGE_A(u + 1, 1);
        PH_SYNC(); MFMA16(0, 0); fence_barrier();
        // ph2: (m0,n1)
        LOADB(0, 1); STAGE_B(u + 1, 1);
        PH_SYNC(); MFMA16(0, 1); fence_barrier();
        // ph3: (m1,n0)
        LOADA(0, 1); STAGE_A(u + 2, 0);
        PH_SYNC(); MFMA16(1, 0); fence_barrier();
        // ph4: (m1,n1); K-tile boundary wait
        STAGE_B(u + 2, 0);
        PH_SYNC(); MFMA16(1, 1);
        VMW4(); fence_barrier();
        // ph5: (m0,n0) of u+1
        LOADA(1, 0); LOADB(1, 0); STAGE_A(u + 2, 1);
        PH_SYNC(); MFMA16(0, 0); fence_barrier();
        // ph6: (m0,n1)
        LOADB(1, 1); STAGE_B(u + 2, 1);
        PH_SYNC(); MFMA16(0, 1); fence_barrier();
        // ph7: (m1,n0)
        LOADA(1, 1); STAGE_A(u + 3, 0);
        PH_SYNC(); MFMA16(1, 0); fence_barrier();
        // ph8: (m1,n1); K-tile boundary wait
        STAGE_B(u + 3, 0);
        PH_SYNC(); MFMA16(1, 1);
        VMW4(); fence_barrier();
    }

    // epilogue: D[m = quad*4 + r][n = l15] per 16x16 frag
#pragma unroll
    for (int mq = 0; mq < 2; ++mq)
#pragma unroll
    for (int i = 0; i < 4; ++i) {
        const int row_base = m0 + mq * 128 + mrow + i * 16 + quad * 4;
#pragma unroll
        for (int nq = 0; nq < 2; ++nq)
#pragma unroll
        for (int j = 0; j < 2; ++j) {
            const int col = n0 + nq * 128 + nrow + j * 16 + l15;
#pragma unroll
            for (int r = 0; r < 4; ++r)
                C[(size_t)(row_base + r) * N_TOT + col] = acc[mq][nq][i][j][r];
        }
    }
}

// ---------------- round-0 fused kernel (fallback if workspace too small) ----------------
__global__ __launch_bounds__(256)
void qgemm_kernel(const float* __restrict__ X, const float* __restrict__ SX,
                  const float* __restrict__ Wq, const float* __restrict__ WS,
                  const float* __restrict__ OFW, float* __restrict__ OUT) {
    __shared__ short As[FBM * LDS_STRIDE];
    __shared__ short Bs[FBN * LDS_STRIDE];

    const int t  = threadIdx.x;
    const int nt = blockIdx.x % (N_TOT / FBN);
    const int mt = blockIdx.x / (N_TOT / FBN);
    const int m0 = mt * FBM;
    const int n0 = nt * FBN;

    const int lane = t & 63;
    const int wave = t >> 6;
    const int wm   = (wave & 1) * 64;
    const int wn   = (wave >> 1) * 64;
    const int l15  = lane & 15;
    const int quad = lane >> 4;

    const int srow = t >> 3;
    const int scol = (t & 7) * 4;

    floatx4 acc[4][4];
#pragma unroll
    for (int i = 0; i < 4; ++i)
#pragma unroll
        for (int j = 0; j < 4; ++j)
            acc[i][j] = (floatx4)0.0f;

    float ascale[4];
#pragma unroll
    for (int j = 0; j < 4; ++j)
        ascale[j] = SX[m0 + j * 32 + srow];

    for (int g = 0; g < NG; ++g) {
        float wsv[4], ofv[4];
#pragma unroll
        for (int j = 0; j < 4; ++j) {
            const int n = n0 + j * 32 + srow;
            wsv[j] = WS[n * NG + g];
            ofv[j] = OFW[n * NG + g];
        }
        for (int kk = 0; kk < GSZ / 32; ++kk) {
            const int k0 = g * GSZ + kk * 32;
            __syncthreads();
#pragma unroll
            for (int j = 0; j < 4; ++j) {
                const int r = j * 32 + srow;
                floatx4 v = *(const floatx4*)&X[(size_t)(m0 + r) * K_TOT + k0 + scol];
                const float s = ascale[j];
                short4v bq;
                bq.x = f2bf_rne(v.x * s);
                bq.y = f2bf_rne(v.y * s);
                bq.z = f2bf_rne(v.z * s);
                bq.w = f2bf_rne(v.w * s);
                *(short4v*)&As[r * LDS_STRIDE + scol] = bq;
            }
#pragma unroll
            for (int j = 0; j < 4; ++j) {
                const int r = j * 32 + srow;
                floatx4 v = *(const floatx4*)&Wq[(size_t)(n0 + r) * K_TOT + k0 + scol];
                const float sc = wsv[j], of = ofv[j];
                short4v bq;
                bq.x = f2bf_rne((v.x - of) * sc);
                bq.y = f2bf_rne((v.y - of) * sc);
                bq.z = f2bf_rne((v.z - of) * sc);
                bq.w = f2bf_rne((v.w - of) * sc);
                *(short4v*)&Bs[r * LDS_STRIDE + scol] = bq;
            }
            __syncthreads();
            short8 af[4], bf[4];
#pragma unroll
            for (int i = 0; i < 4; ++i)
                af[i] = *(const short8*)&As[(wm + i * 16 + l15) * LDS_STRIDE + quad * 8];
#pragma unroll
            for (int i = 0; i < 4; ++i)
                bf[i] = *(const short8*)&Bs[(wn + i * 16 + l15) * LDS_STRIDE + quad * 8];
#pragma unroll
            for (int i = 0; i < 4; ++i)
#pragma unroll
                for (int j = 0; j < 4; ++j)
                    acc[i][j] = __builtin_amdgcn_mfma_f32_16x16x32_bf16(af[i], bf[j], acc[i][j], 0, 0, 0);
        }
    }

#pragma unroll
    for (int i = 0; i < 4; ++i) {
        const int row_base = m0 + wm + i * 16 + quad * 4;
#pragma unroll
        for (int j = 0; j < 4; ++j) {
            const int col = n0 + wn + j * 16 + l15;
#pragma unroll
            for (int r = 0; r < 4; ++r)
                OUT[(size_t)(row_base + r) * N_TOT + col] = acc[i][j][r];
        }
    }
}

extern "C" void kernel_launch(void* const* d_in, const int* in_sizes, int n_in,
                              void* d_out, int out_size, void* d_ws, size_t ws_size,
                              hipStream_t stream) {
    const float* X   = (const float*)d_in[0];   // quantized_x [B,S,IN]
    const float* SX  = (const float*)d_in[1];   // scales_x    [B,S,1]
    const float* Wq  = (const float*)d_in[2];   // weight      [OUT,IN]
    const float* WS  = (const float*)d_in[3];   // weight_scales [OUT,G]
    const float* OFW = (const float*)d_in[4];   // offset_w    [OUT,G]
    float* out = (float*)d_out;

    const size_t xb_bytes = (size_t)M_TOT * K_TOT * 2;   // 64 MiB
    const size_t wb_bytes = (size_t)N_TOT * K_TOT * 2;   // 86 MiB

    if (ws_size >= xb_bytes + wb_bytes) {
        unsigned short* Xb = (unsigned short*)d_ws;
        unsigned short* Wb = (unsigned short*)((char*)d_ws + xb_bytes);
        const int grid_x = (int)(((size_t)M_TOT * K_TOT / 8) / 256);    // 16384
        const int grid_w = (int)(((size_t)N_TOT * K_TOT / 8) / 256);    // 22016
        const int grid_gemm = (M_TOT / BM) * (N_TOT / BN);              // 32*43 = 1376
        dequant_x_kernel<<<grid_x, 256, 0, stream>>>(X, SX, Xb);
        dequant_w_kernel<<<grid_w, 256, 0, stream>>>(Wq, WS, OFW, Wb);
        gemm_bf16_kernel<<<grid_gemm, 512, 0, stream>>>(Xb, Wb, out);
    } else {
        const int grid = (M_TOT / FBM) * (N_TOT / FBN);
        qgemm_kernel<<<grid, 256, 0, stream>>>(X, SX, Wq, WS, OFW, out);
    }
}